// Round 4
// baseline (659.448 us; speedup 1.0000x reference)
//
#include <hip/hip_runtime.h>
#include <hip/hip_bf16.h>

#define HEADS 8
#define F_IN 256
#define OUT 64
#define NOUT 512   // HEADS*OUT

typedef __attribute__((ext_vector_type(8))) short bf16x8;
typedef __attribute__((ext_vector_type(4))) float f32x4;

__device__ __forceinline__ short f2b(float f) {
  __hip_bfloat16 h = __float2bfloat16(f);
  return *(short*)&h;
}
__device__ __forceinline__ float blo(unsigned u) { return __uint_as_float(u << 16); }
__device__ __forceinline__ float bhi(unsigned u) { return __uint_as_float(u & 0xffff0000u); }

// ---------------------------------------------------------------------------
// Convert f32 -> bf16 bits, 8 elems/thread
// ---------------------------------------------------------------------------
__global__ __launch_bounds__(256) void conv_kernel(
    const float* __restrict__ src, short* __restrict__ dst, int n8)
{
  int i = blockIdx.x * 256 + threadIdx.x;
  if (i >= n8) return;
  const float4 a = *(const float4*)(src + (size_t)i * 8);
  const float4 b = *(const float4*)(src + (size_t)i * 8 + 4);
  short r[8] = { f2b(a.x), f2b(a.y), f2b(a.z), f2b(a.w),
                 f2b(b.x), f2b(b.y), f2b(b.z), f2b(b.w) };
  *(uint4*)(dst + (size_t)i * 8) = *(uint4*)r;
}

// ---------------------------------------------------------------------------
// MFMA GEMM, operand-swapped: D = W·x^T so D[row=o][col=n].
// Lane's 4 acc regs = 4 consecutive o -> packed 8B stores into interleaved
// t2[n][h*64+o]. Fused Ar epilogue (Al cancels in row-softmax).
// Block 256 thr; tile 128 nodes x 64 outs (one head); BK=64.
// ---------------------------------------------------------------------------
__global__ __launch_bounds__(256) void gemm_mfma(
    const short* __restrict__ xb, const short* __restrict__ W2,
    const float* __restrict__ As, const float* __restrict__ Asb,
    short* __restrict__ t2, float* __restrict__ Ar, int N)
{
  __shared__ __align__(16) short as[128][72];  // 144B stride: 2-way alias (free)
  __shared__ __align__(16) short bs[64][72];
  const int tid = threadIdx.x;
  const int h  = blockIdx.x;
  const int n0 = blockIdx.y * 128;
  const int lane = tid & 63, wave = tid >> 6;
  const int lcol = lane & 15, quad = lane >> 4;
  const short* Wh = W2 + h * OUT * F_IN;

  f32x4 acc[4][2] = {};   // [o-tile][n-tile]

  for (int k0 = 0; k0 < F_IN; k0 += 64) {
    __syncthreads();
    #pragma unroll
    for (int p = 0; p < 4; ++p) {
      int id = tid + 256 * p;
      int r = id >> 3, s = id & 7;
      int n = n0 + r;
      uint4 v = make_uint4(0, 0, 0, 0);
      if (n < N) v = *(const uint4*)(xb + (size_t)n * F_IN + k0 + s * 8);
      *(uint4*)&as[r][s * 8] = v;
    }
    #pragma unroll
    for (int p = 0; p < 2; ++p) {
      int id = tid + 256 * p;
      int r = id >> 3, s = id & 7;
      uint4 v = *(const uint4*)(Wh + r * F_IN + k0 + s * 8);
      *(uint4*)&bs[r][s * 8] = v;
    }
    __syncthreads();
    #pragma unroll
    for (int ks = 0; ks < 2; ++ks) {
      bf16x8 wf[4], xf[2];
      #pragma unroll
      for (int i = 0; i < 4; ++i)
        wf[i] = *(const bf16x8*)&bs[i * 16 + lcol][ks * 32 + quad * 8];
      #pragma unroll
      for (int j = 0; j < 2; ++j)
        xf[j] = *(const bf16x8*)&as[wave * 32 + j * 16 + lcol][ks * 32 + quad * 8];
      #pragma unroll
      for (int i = 0; i < 4; ++i)
        #pragma unroll
        for (int j = 0; j < 2; ++j)
          acc[i][j] = __builtin_amdgcn_mfma_f32_16x16x32_bf16(
              wf[i], xf[j], acc[i][j], 0, 0, 0);
    }
  }

  // epilogue: o = i*16 + quad*4 + reg; n = n0 + wave*32 + j*16 + lcol
  float4 arw4[4];
  #pragma unroll
  for (int i = 0; i < 4; ++i)
    arw4[i] = *(const float4*)(As + h * 2 * OUT + OUT + i * 16 + quad * 4);
  const float arb = Asb[h * 2 + 1];

  #pragma unroll
  for (int j = 0; j < 2; ++j) {
    const int n = n0 + wave * 32 + j * 16 + lcol;
    float p = 0.f;
    #pragma unroll
    for (int i = 0; i < 4; ++i) {
      p = fmaf(acc[i][j][0], arw4[i].x, p);
      p = fmaf(acc[i][j][1], arw4[i].y, p);
      p = fmaf(acc[i][j][2], arw4[i].z, p);
      p = fmaf(acc[i][j][3], arw4[i].w, p);
    }
    p += __shfl_xor(p, 16);
    p += __shfl_xor(p, 32);
    if (n < N) {
      if (quad == 0) Ar[(size_t)h * N + n] = p + arb;
      short* tn = t2 + (size_t)n * NOUT + h * OUT + quad * 4;
      #pragma unroll
      for (int i = 0; i < 4; ++i) {
        short r4[4] = { f2b(acc[i][j][0]), f2b(acc[i][j][1]),
                        f2b(acc[i][j][2]), f2b(acc[i][j][3]) };
        *(uint2*)(tn + i * 16) = *(uint2*)r4;
      }
    }
  }
}

// ---------------------------------------------------------------------------
// CSR build: histogram -> 3-phase multi-block scan -> counting-sort scatter
// ---------------------------------------------------------------------------
#define SB 128

__global__ void hist_kernel(const int* __restrict__ row, int* __restrict__ deg, int E)
{
  int e = blockIdx.x * 256 + threadIdx.x;
  if (e < E) atomicAdd(&deg[row[e]], 1);
}

__global__ __launch_bounds__(256) void scan1_kernel(
    const int* __restrict__ deg, int* __restrict__ bsum, int N)
{
  const int b = blockIdx.x;
  const int C = (N + SB - 1) / SB;
  const int base = b * C;
  int s = 0;
  for (int i = threadIdx.x; i < C; i += 256) {
    int idx = base + i;
    if (idx < N) s += deg[idx];
  }
  #pragma unroll
  for (int off = 32; off >= 1; off >>= 1) s += __shfl_xor(s, off);
  __shared__ int sm[4];
  if ((threadIdx.x & 63) == 0) sm[threadIdx.x >> 6] = s;
  __syncthreads();
  if (threadIdx.x == 0) bsum[b] = sm[0] + sm[1] + sm[2] + sm[3];
}

__global__ __launch_bounds__(SB) void scan2_kernel(
    const int* __restrict__ bsum, int* __restrict__ bofs, int* __restrict__ total)
{
  __shared__ int sd[SB];
  const int t = threadIdx.x;
  int v = bsum[t];
  sd[t] = v;
  __syncthreads();
  for (int off = 1; off < SB; off <<= 1) {
    int u = (t >= off) ? sd[t - off] : 0;
    __syncthreads();
    sd[t] += u;
    __syncthreads();
  }
  bofs[t] = sd[t] - v;
  if (t == SB - 1) total[0] = sd[t];
}

__global__ __launch_bounds__(256) void scan3_kernel(
    const int* __restrict__ deg, const int* __restrict__ bofs,
    int* __restrict__ row_ptr, int N)
{
  const int b = blockIdx.x;
  const int C = (N + SB - 1) / SB;
  const int CH = (C + 255) / 256;
  const int base = b * C;
  const int lim = min(base + C, N);
  const int start = base + threadIdx.x * CH;
  int vals[4];
  int s = 0;
  for (int i = 0; i < CH; ++i) {
    int idx = start + i;
    vals[i] = (idx < lim) ? deg[idx] : 0;
    s += vals[i];
  }
  __shared__ int sd[256];
  sd[threadIdx.x] = s;
  __syncthreads();
  for (int off = 1; off < 256; off <<= 1) {
    int u = (threadIdx.x >= off) ? sd[threadIdx.x - off] : 0;
    __syncthreads();
    sd[threadIdx.x] += u;
    __syncthreads();
  }
  int excl = sd[threadIdx.x] - s + bofs[b];
  for (int i = 0; i < CH; ++i) {
    int idx = start + i;
    if (idx < lim) { row_ptr[idx] = excl; excl += vals[i]; }
  }
}

__global__ void scatter_kernel(const int* __restrict__ row, const int* __restrict__ col,
                               const int* __restrict__ row_ptr, int* __restrict__ cursor,
                               int* __restrict__ col_sorted, int E)
{
  int e = blockIdx.x * 256 + threadIdx.x;
  if (e < E) {
    int r = row[e];
    int pos = atomicAdd(&cursor[r], 1);
    col_sorted[row_ptr[r] + pos] = col[e];
  }
}

// ---------------------------------------------------------------------------
// Per-head global max of Ar, then Wexp2[n][h] = exp(Ar[h][n]-m[h]).
// (Per-row max redundant: softmax shift-invariant; Ar ~ N(0,1).)
// ---------------------------------------------------------------------------
__global__ __launch_bounds__(256) void maxred_kernel(
    const float* __restrict__ Ar, float* __restrict__ m, int N)
{
  const int h = blockIdx.x;
  const float* a = Ar + (size_t)h * N;
  float mm = -1e30f;
  for (int i = threadIdx.x; i < N; i += 256) mm = fmaxf(mm, a[i]);
  #pragma unroll
  for (int off = 32; off >= 1; off >>= 1) mm = fmaxf(mm, __shfl_xor(mm, off));
  __shared__ float sm[4];
  if ((threadIdx.x & 63) == 0) sm[threadIdx.x >> 6] = mm;
  __syncthreads();
  if (threadIdx.x == 0)
    m[h] = fmaxf(fmaxf(sm[0], sm[1]), fmaxf(sm[2], sm[3]));
}

__global__ __launch_bounds__(256) void expw_kernel(
    const float* __restrict__ Ar, const float* __restrict__ m,
    float* __restrict__ Wexp2, int N)
{
  const int n = blockIdx.x * 256 + threadIdx.x;
  const int h = blockIdx.y;
  if (n < N) Wexp2[(size_t)n * HEADS + h] = __expf(Ar[(size_t)h * N + n] - m[h]);
}

// ---------------------------------------------------------------------------
// Aggregation v3: one wave per row; lane = (head = lane>>3, oct = lane&7).
// Per edge the wave reads t2[c] (1KB, all heads) as a fully-coalesced
// 64x16B load. Col indices are wave-uniform -> SGPR base via readfirstlane.
// Each lane's sw is already the full denominator: NO cross-lane reduction.
// 4-edge batches with next-batch col prefetch (4KB in flight per wave).
// ---------------------------------------------------------------------------
__global__ __launch_bounds__(256) void agg_kernel(
    const int* __restrict__ row_ptr, const int* __restrict__ col_sorted,
    const float* __restrict__ Wexp2, const short* __restrict__ t2,
    const float* __restrict__ Wb, float* __restrict__ out, int N)
{
  const int lane = threadIdx.x & 63;
  const int wave = threadIdx.x >> 6;
  const int row = blockIdx.x * 4 + wave;
  if (row >= N) return;
  const int start = __builtin_amdgcn_readfirstlane(row_ptr[row]);
  const int end   = __builtin_amdgcn_readfirstlane(row_ptr[row + 1]);
  const int hh = lane >> 3;

  float acc[8];
  #pragma unroll
  for (int i = 0; i < 8; ++i) acc[i] = 0.f;
  float sw = 0.f;

  if (end > start) {
    int cc[4];
    #pragma unroll
    for (int j = 0; j < 4; ++j)
      cc[j] = col_sorted[min(start + j, end - 1)];

    for (int eb = start; eb < end; eb += 4) {
      int cl[4];
      #pragma unroll
      for (int j = 0; j < 4; ++j)
        cl[j] = __builtin_amdgcn_readfirstlane(cc[j]);
      const int ebn = eb + 4;
      if (ebn < end) {
        #pragma unroll
        for (int j = 0; j < 4; ++j)
          cc[j] = col_sorted[min(ebn + j, end - 1)];
      }
      uint4 tv[4];
      float wv[4];
      #pragma unroll
      for (int j = 0; j < 4; ++j) {
        tv[j] = *(const uint4*)(t2 + (size_t)cl[j] * NOUT + lane * 8);
        wv[j] = (eb + j < end) ? Wexp2[cl[j] * HEADS + hh] : 0.f;
      }
      #pragma unroll
      for (int j = 0; j < 4; ++j) {
        const float w = wv[j];
        sw += w;
        acc[0] = fmaf(w, blo(tv[j].x), acc[0]);
        acc[1] = fmaf(w, bhi(tv[j].x), acc[1]);
        acc[2] = fmaf(w, blo(tv[j].y), acc[2]);
        acc[3] = fmaf(w, bhi(tv[j].y), acc[3]);
        acc[4] = fmaf(w, blo(tv[j].z), acc[4]);
        acc[5] = fmaf(w, bhi(tv[j].z), acc[5]);
        acc[6] = fmaf(w, blo(tv[j].w), acc[6]);
        acc[7] = fmaf(w, bhi(tv[j].w), acc[7]);
      }
    }
  }

  // epilogue: lane writes its 8 outputs; Wb offset h*64+oct*8 == lane*8
  const float inv = (sw > 0.f) ? 1.f / sw : 0.f;
  const float4 b0 = *(const float4*)(Wb + lane * 8);
  const float4 b1 = *(const float4*)(Wb + lane * 8 + 4);
  const float bb[8] = { b0.x, b0.y, b0.z, b0.w, b1.x, b1.y, b1.z, b1.w };
  float r[8];
  #pragma unroll
  for (int i = 0; i < 8; ++i) {
    float y = acc[i] * inv + bb[i];
    r[i] = (y > 0.f) ? y : (__expf(y) - 1.f);
  }
  float* op = out + (size_t)row * NOUT + lane * 8;
  *(float4*)op       = make_float4(r[0], r[1], r[2], r[3]);
  *((float4*)op + 1) = make_float4(r[4], r[5], r[6], r[7]);
}

// ---------------------------------------------------------------------------
extern "C" void kernel_launch(void* const* d_in, const int* in_sizes, int n_in,
                              void* d_out, int out_size, void* d_ws, size_t ws_size,
                              hipStream_t stream)
{
  const float* x    = (const float*)d_in[0];
  const int*   erow = (const int*)d_in[1];
  const int*   ecol = (const int*)d_in[2];
  const float* Ws   = (const float*)d_in[3];
  const float* Wb   = (const float*)d_in[4];
  const float* As   = (const float*)d_in[5];
  const float* Asb  = (const float*)d_in[6];
  float* out = (float*)d_out;
  const int N = in_sizes[0] / F_IN;
  const int E = in_sizes[1];

  char* p = (char*)d_ws;
  short* t2      = (short*)p; p += (size_t)N * NOUT * sizeof(short);
  short* xb      = (short*)p; p += (size_t)N * F_IN * sizeof(short);
  short* W2      = (short*)p; p += (size_t)NOUT * F_IN * sizeof(short);
  float* Ar      = (float*)p; p += (size_t)HEADS * N * sizeof(float);
  float* Wexp2   = (float*)p; p += (size_t)N * HEADS * sizeof(float);
  float* mbuf    = (float*)p; p += 64 * sizeof(float);
  int* row_ptr   = (int*)p;   p += (size_t)(N + 1) * sizeof(int);
  int* deg       = (int*)p;   p += (size_t)N * sizeof(int);   // deg+cursor adjacent:
  int* cursor    = (int*)p;   p += (size_t)N * sizeof(int);   // one memset covers both
  int* bsum      = (int*)p;   p += SB * sizeof(int);
  int* bofs      = (int*)p;   p += SB * sizeof(int);
  int* col_sorted= (int*)p;   p += (size_t)E * sizeof(int);

  hipMemsetAsync(deg, 0, (size_t)2 * N * sizeof(int), stream);

  // CSR build
  hist_kernel<<<dim3((E + 255) / 256), dim3(256), 0, stream>>>(erow, deg, E);
  scan1_kernel<<<dim3(SB), dim3(256), 0, stream>>>(deg, bsum, N);
  scan2_kernel<<<dim3(1), dim3(SB), 0, stream>>>(bsum, bofs, row_ptr + N);
  scan3_kernel<<<dim3(SB), dim3(256), 0, stream>>>(deg, bofs, row_ptr, N);
  scatter_kernel<<<dim3((E + 255) / 256), dim3(256), 0, stream>>>(
      erow, ecol, row_ptr, cursor, col_sorted, E);

  // bf16 conversions
  conv_kernel<<<dim3((N * F_IN / 8 + 255) / 256), dim3(256), 0, stream>>>(
      x, xb, N * F_IN / 8);
  conv_kernel<<<dim3((NOUT * F_IN / 8 + 255) / 256), dim3(256), 0, stream>>>(
      Ws, W2, NOUT * F_IN / 8);

  // MFMA GEMM + fused Ar
  dim3 gg(HEADS, (N + 127) / 128);
  gemm_mfma<<<gg, dim3(256), 0, stream>>>(xb, W2, As, Asb, t2, Ar, N);

  maxred_kernel<<<dim3(HEADS), dim3(256), 0, stream>>>(Ar, mbuf, N);
  dim3 ge((N + 255) / 256, HEADS);
  expw_kernel<<<ge, dim3(256), 0, stream>>>(Ar, mbuf, Wexp2, N);

  agg_kernel<<<dim3((N + 3) / 4), dim3(256), 0, stream>>>(
      row_ptr, col_sorted, Wexp2, t2, Wb, out, N);
}